// Round 8
// baseline (694.621 us; speedup 1.0000x reference)
//
#include <hip/hip_runtime.h>
#include <hip/hip_bf16.h>

// Problem constants (fixed by the reference setup)
#define NNODES   50000
#define NGRAPHS  64
#define INDIM    1024
#define HIDC     64      // channels per head
#define HEADS1   4
#define F1       (HEADS1*HIDC)   // 256
#define NEG_SLOPE 0.2f

// ---------------------------------------------------------------------------
// Workspace layout (4-byte words). All vector-accessed buffers 16B-aligned.
#define WS_COUNTS   0                    // int[50000]
#define WS_ZEROLEN  50000                // words to zero (counts only)
#define WS_INDPTR   54208                // int[50001]
#define WS_CURSOR   104256               // int[50000]
#define WS_CSRSRC   154304               // int[850000]
#define WS_CSRDST   1004304              // (dead - kept for layout stability)
#define WS_BSUM     1854304              // int[64]
#define WS_ALS1     1854368              // float[200000]
#define WS_ALD1     2054368              // float[200000]
#define WS_ALS2     2254368              // float[50000]
#define WS_ALD2     2304368              // float[50000]
#define WS_BP       2354368              // ushort[262144] (packed bf16 W1)
#define WS_BP2      2485440              // ushort[16384]  (packed bf16 W2)
#define WS_H1B      2493632              // ushort[12,800,000] bf16 h1
#define WS_X2B      8893632              // ushort[12,800,000] bf16 x2
#define WS_H2B      15293632             // ushort[3,200,000]  bf16 h2
#define WS_HFIN     16893632             // float[3,200,000]
#define WS_XB       20093632             // ushort[51,200,000] bf16 x (row-major)

typedef __attribute__((ext_vector_type(8))) short bf16x8;
typedef __attribute__((ext_vector_type(4))) float f32x4;

__device__ __forceinline__ ushort f2bf(float f) {
    union { float f; uint u; } v; v.f = f;
    uint r = v.u + 0x7fff + ((v.u >> 16) & 1);   // round-to-nearest-even
    return (ushort)(r >> 16);
}
__device__ __forceinline__ float bf2f(ushort u) {
    union { uint u; float f; } v; v.u = (uint)u << 16; return v.f;
}

// ---------------------------------------------------------------------------
// Streaming x fp32 -> bf16 (row-major, fully coalesced both sides).
__global__ void cvt_x_kernel(const float* __restrict__ x, ushort* __restrict__ xb,
                             long n8) {
    long i = blockIdx.x * (long)blockDim.x + threadIdx.x;
    long stride = (long)gridDim.x * blockDim.x;
    for (; i < n8; i += stride) {
        const float4* p = (const float4*)(x + i * 8);
        float4 a = p[0], b = p[1];
        union { ushort u[8]; uint4 v; } o;
        o.u[0] = f2bf(a.x); o.u[1] = f2bf(a.y); o.u[2] = f2bf(a.z); o.u[3] = f2bf(a.w);
        o.u[4] = f2bf(b.x); o.u[5] = f2bf(b.y); o.u[6] = f2bf(b.z); o.u[7] = f2bf(b.w);
        *(uint4*)(xb + i * 8) = o.v;
    }
}

// ---------------------------------------------------------------------------
// Fused prelude: pack W1 + pack W2 into bf16 MFMA-B fragment order, zero counts.
// blocks [0,1024): W1, [1024,1088): W2, [1088,1284): zero counts.
__global__ void prep_kernel(const float* __restrict__ W1, const float* __restrict__ W2,
                            ushort* __restrict__ Bp1, ushort* __restrict__ Bp2,
                            int* __restrict__ counts) {
    int b = blockIdx.x;
    int tid = threadIdx.x;
    if (b < 1024) {                      // pack W1 [1024,256]
        int o = b * 256 + tid;           // 0 .. 262143
        int j = o & 7;
        int lane = (o >> 3) & 63;
        int kchunk = (o >> 9) & 31;
        int ntile = o >> 14;
        int k = kchunk * 32 + (lane >> 4) * 8 + j;
        int n = ntile * 16 + (lane & 15);
        Bp1[o] = f2bf(W1[k * 256 + n]);
    } else if (b < 1088) {               // pack W2 [256,64]
        int o = (b - 1024) * 256 + tid;  // 0 .. 16383
        int j = o & 7;
        int lane = (o >> 3) & 63;
        int kchunk = (o >> 9) & 7;
        int ntile = o >> 12;
        int k = kchunk * 32 + (lane >> 4) * 8 + j;
        int n = ntile * 16 + (lane & 15);
        Bp2[o] = f2bf(W2[k * 64 + n]);
    } else {                             // zero counts
        int i = (b - 1088) * 256 + tid;
        if (i < NNODES) counts[i] = 0;
    }
}

__global__ void hist_kernel(const int* __restrict__ dst, int* __restrict__ counts, int E) {
    int i = blockIdx.x * blockDim.x + threadIdx.x;
    if (i < E) atomicAdd(&counts[dst[i]], 1);
}

// --- 3-kernel multi-block scan -------------------------------------------
__global__ __launch_bounds__(1024) void scan1_kernel(const int* __restrict__ counts,
                                                     int* __restrict__ indptr,
                                                     int* __restrict__ bsum, int N) {
    __shared__ int sm[1024];
    int b = blockIdx.x;
    int i = b * 1024 + (int)threadIdx.x;
    int v = (i < N) ? counts[i] : 0;
    sm[threadIdx.x] = v;
    __syncthreads();
    for (int off = 1; off < 1024; off <<= 1) {
        int t = (threadIdx.x >= (unsigned)off) ? sm[threadIdx.x - off] : 0;
        __syncthreads();
        sm[threadIdx.x] += t;
        __syncthreads();
    }
    if (i < N) indptr[i + 1] = sm[threadIdx.x];
    if (threadIdx.x == 1023) bsum[b] = sm[1023];
}

__global__ void scan2_kernel(int* __restrict__ bsum, int nb) {
    int lane = threadIdx.x;
    int v = (lane < nb) ? bsum[lane] : 0;
    int orig = v;
    #pragma unroll
    for (int off = 1; off < 64; off <<= 1) {
        int t = __shfl_up(v, off, 64);
        if (lane >= off) v += t;
    }
    if (lane < nb) bsum[lane] = v - orig;   // exclusive
}

__global__ __launch_bounds__(1024) void scan3_kernel(const int* __restrict__ counts,
                                                     int* __restrict__ indptr,
                                                     int* __restrict__ cursor,
                                                     const int* __restrict__ bsum, int N) {
    int i = blockIdx.x * 1024 + (int)threadIdx.x;
    if (i == 0) indptr[0] = 0;
    if (i < N) {
        int incl = indptr[i + 1] + bsum[blockIdx.x];
        indptr[i + 1] = incl;
        cursor[i] = incl - counts[i];
    }
}

// csr_dst was dead (never read) -> removed; only csr_src is built.
__global__ void fill_kernel(const int* __restrict__ src, const int* __restrict__ dst,
                            int* __restrict__ cursor, int* __restrict__ csr_src, int E) {
    int i = blockIdx.x * blockDim.x + threadIdx.x;
    if (i < E) {
        int d = dst[i];
        int pos = atomicAdd(&cursor[d], 1);
        csr_src[pos] = src[i];
    }
}

// ---------------------------------------------------------------------------
// bf16 MFMA GEMM, layer 1: h1b[M,256](bf16) = xb[M,1024](bf16) @ W1.
// DIRECT register-fragment GEMM (gemm2's proven structure scaled up): NO LDS,
// NO barriers, no in-loop conversion. Per kc: 4 A-frag loads straight from
// row-major bf16 xb (16B/lane; a wave touches 16 rows x 64B lines -> fully
// coalesced at line granularity) + 8 B-frag loads from packed Bp (L2) + 32
// MFMAs. Waves are completely independent -> no rendezvous stalls; compiler
// pipelines loads across kc freely. Epilogue fuses attention logits.
__global__ __launch_bounds__(256) void gemm1_mfma(const ushort* __restrict__ Ab,
                                                  const ushort* __restrict__ Bp,
                                                  ushort* __restrict__ C,
                                                  const float* __restrict__ asrc,
                                                  const float* __restrict__ adst,
                                                  float* __restrict__ als,
                                                  float* __restrict__ ald,
                                                  int M) {
    const int K = 1024, N = 256;
    int tid = threadIdx.x;
    int lane = tid & 63;
    int w = tid >> 6;
    int wm = w >> 1, wn = w & 1;          // wave covers 64 rows x 128 cols
    int m0 = blockIdx.x * 128;

    // A-frag row pointers: lane holds A[r][kc*32 + (lane>>4)*8 + 0..7]
    const ushort* arow[4];
    #pragma unroll
    for (int mt = 0; mt < 4; ++mt) {
        int r = m0 + wm * 64 + mt * 16 + (lane & 15);
        if (r >= M) r = M - 1;
        arow[mt] = Ab + (size_t)r * K + (lane >> 4) * 8;
    }
    const ushort* bbase[8];
    #pragma unroll
    for (int nt = 0; nt < 8; ++nt) {
        int ntile = wn * 8 + nt;
        bbase[nt] = Bp + ((size_t)(ntile * 32) * 64 + lane) * 8;
    }

    f32x4 acc[4][8] = {};

    #pragma unroll 2
    for (int kc = 0; kc < 32; ++kc) {
        bf16x8 afr[4];
        #pragma unroll
        for (int mt = 0; mt < 4; ++mt)
            afr[mt] = *(const bf16x8*)(arow[mt] + kc * 32);
        #pragma unroll
        for (int nt = 0; nt < 8; ++nt) {
            bf16x8 bfr = *(const bf16x8*)(bbase[nt] + (size_t)kc * 512);
            #pragma unroll
            for (int mt = 0; mt < 4; ++mt)
                acc[mt][nt] = __builtin_amdgcn_mfma_f32_16x16x32_bf16(afr[mt], bfr, acc[mt][nt], 0, 0, 0);
        }
    }

    // epilogue: C write (bf16) + fused attention logits (2 heads per wave)
    float a_s[8], a_d[8];
    #pragma unroll
    for (int nt = 0; nt < 8; ++nt) {
        int col = wn * 128 + nt * 16 + (lane & 15);   // head = col>>6
        a_s[nt] = asrc[col];
        a_d[nt] = adst[col];
    }
    #pragma unroll
    for (int mt = 0; mt < 4; ++mt) {
        #pragma unroll
        for (int nt = 0; nt < 8; ++nt) {
            int col = wn * 128 + nt * 16 + (lane & 15);
            #pragma unroll
            for (int r = 0; r < 4; ++r) {
                int row = m0 + wm * 64 + mt * 16 + (lane >> 4) * 4 + r;
                if (row < M) C[(size_t)row * N + col] = f2bf(acc[mt][nt][r]);
            }
        }
        #pragma unroll
        for (int hg = 0; hg < 2; ++hg) {         // head group: nt 4hg..4hg+3
            int head = wn * 2 + hg;
            #pragma unroll
            for (int r = 0; r < 4; ++r) {
                int row = m0 + wm * 64 + mt * 16 + (lane >> 4) * 4 + r;
                float s = 0.f, d = 0.f;
                #pragma unroll
                for (int q = 0; q < 4; ++q) {
                    float c = acc[mt][4 * hg + q][r];
                    s = fmaf(c, a_s[4 * hg + q], s);
                    d = fmaf(c, a_d[4 * hg + q], d);
                }
                #pragma unroll
                for (int off = 1; off < 16; off <<= 1) {
                    s += __shfl_xor(s, off, 64);
                    d += __shfl_xor(d, off, 64);
                }
                if ((lane & 15) == 0 && row < M) {
                    als[row * 4 + head] = s;
                    ald[row * 4 + head] = d;
                }
            }
        }
    }
}

// ---------------------------------------------------------------------------
// bf16 MFMA GEMM, layer 2: h2b[M,64](bf16) = x2b[M,256](bf16) @ W2.
// R1-exact form (128 rows/block, wave = 32 rows x 64 cols).
// Epilogue fuses attention logits als2/ald2 (single head).
__global__ __launch_bounds__(256) void gemm2_mfma(const ushort* __restrict__ Ab,
                                                  const ushort* __restrict__ Bp,
                                                  ushort* __restrict__ C,
                                                  const float* __restrict__ asrc,
                                                  const float* __restrict__ adst,
                                                  float* __restrict__ als,
                                                  float* __restrict__ ald,
                                                  int M) {
    int tid = threadIdx.x;
    int lane = tid & 63;
    int w = tid >> 6;
    int m0 = blockIdx.x * 128 + w * 32;

    f32x4 acc[2][4] = {};
    #pragma unroll 2
    for (int kc = 0; kc < 8; ++kc) {
        bf16x8 afr[2];
        #pragma unroll
        for (int mt = 0; mt < 2; ++mt) {
            int r = m0 + mt * 16 + (lane & 15);
            if (r >= M) r = M - 1;
            afr[mt] = *(const bf16x8*)&Ab[(size_t)r * 256 + kc * 32 + (lane >> 4) * 8];
        }
        #pragma unroll
        for (int nt = 0; nt < 4; ++nt) {
            bf16x8 bfr = *(const bf16x8*)&Bp[((nt * 8 + kc) * 64 + lane) * 8];
            acc[0][nt] = __builtin_amdgcn_mfma_f32_16x16x32_bf16(afr[0], bfr, acc[0][nt], 0, 0, 0);
            acc[1][nt] = __builtin_amdgcn_mfma_f32_16x16x32_bf16(afr[1], bfr, acc[1][nt], 0, 0, 0);
        }
    }
    float a_s[4], a_d[4];
    #pragma unroll
    for (int nt = 0; nt < 4; ++nt) {
        a_s[nt] = asrc[nt * 16 + (lane & 15)];
        a_d[nt] = adst[nt * 16 + (lane & 15)];
    }
    #pragma unroll
    for (int mt = 0; mt < 2; ++mt) {
        #pragma unroll
        for (int nt = 0; nt < 4; ++nt) {
            int col = nt * 16 + (lane & 15);
            #pragma unroll
            for (int r = 0; r < 4; ++r) {
                int row = m0 + mt * 16 + (lane >> 4) * 4 + r;
                if (row < M) C[(size_t)row * 64 + col] = f2bf(acc[mt][nt][r]);
            }
        }
        #pragma unroll
        for (int r = 0; r < 4; ++r) {
            int row = m0 + mt * 16 + (lane >> 4) * 4 + r;
            float s = 0.f, d = 0.f;
            #pragma unroll
            for (int nt = 0; nt < 4; ++nt) {
                float c = acc[mt][nt][r];
                s = fmaf(c, a_s[nt], s);
                d = fmaf(c, a_d[nt], d);
            }
            #pragma unroll
            for (int off = 1; off < 16; off <<= 1) {
                s += __shfl_xor(s, off, 64);
                d += __shfl_xor(d, off, 64);
            }
            if ((lane & 15) == 0 && row < M) {
                als[row] = s;
                ald[row] = d;
            }
        }
    }
}

// ---------------------------------------------------------------------------
__device__ __forceinline__ float wave_reduce_sum(float v) {
    #pragma unroll
    for (int off = 32; off > 0; off >>= 1) v += __shfl_xor(v, off, 64);
    return v;
}

__device__ __forceinline__ float edge_w(float e) {
    e = (e > 0.f) ? e : NEG_SLOPE * e;
    return __expf(e);
}

// agg1: 4 nodes/block, one full wave per node (512-B row across 64 lanes).
// Two-phase per <=64-edge chunk: staged srcs + precomputed exp-weights in
// wave-private LDS, then an unrolled gather loop with >=4 independent row
// gathers in flight. No __syncthreads anywhere. (R1-exact)
__global__ __launch_bounds__(256) void agg1_kernel(const ushort* __restrict__ h,
                                                   const float* __restrict__ als,
                                                   const float* __restrict__ ald,
                                                   const int* __restrict__ indptr,
                                                   const int* __restrict__ csr_src,
                                                   const float* __restrict__ bias,
                                                   ushort* __restrict__ out, int N) {
    __shared__ int   s_s[4][64];
    __shared__ float s_w[4][64][4];
    int wv   = threadIdx.x >> 6;
    int lane = threadIdx.x & 63;
    int n = blockIdx.x * 4 + wv;
    if (n >= N) return;
    int hd = lane >> 4;
    int beg = indptr[n], end = indptr[n + 1];
    float4 aldv = *(const float4*)&ald[n * 4];

    float4 acc = make_float4(0.f, 0.f, 0.f, 0.f);
    float den = 0.f;

    for (int base = beg; base < end; base += 64) {
        int cnt = end - base; if (cnt > 64) cnt = 64;
        if (lane < cnt) {
            int s = csr_src[base + lane];
            s_s[wv][lane] = s;
            float4 av = *(const float4*)&als[s * 4];
            s_w[wv][lane][0] = edge_w(av.x + aldv.x);
            s_w[wv][lane][1] = edge_w(av.y + aldv.y);
            s_w[wv][lane][2] = edge_w(av.z + aldv.z);
            s_w[wv][lane][3] = edge_w(av.w + aldv.w);
        }
        // wave-private LDS, lock-step wave: no barrier needed
        #pragma unroll 4
        for (int e = 0; e < cnt; ++e) {
            int s = s_s[wv][e];                     // broadcast
            float wt = s_w[wv][e][hd];              // 4-addr broadcast
            ushort4 a = *(const ushort4*)&h[(size_t)s * 256 + lane * 4];
            acc.x = fmaf(wt, bf2f(a.x), acc.x);
            acc.y = fmaf(wt, bf2f(a.y), acc.y);
            acc.z = fmaf(wt, bf2f(a.z), acc.z);
            acc.w = fmaf(wt, bf2f(a.w), acc.w);
            den += wt;
        }
    }

    float inv = 1.0f / den;
    float4 bv = *(const float4*)&bias[lane * 4];
    float o0 = acc.x * inv + bv.x, o1 = acc.y * inv + bv.y;
    float o2 = acc.z * inv + bv.z, o3 = acc.w * inv + bv.w;
    o0 = (o0 > 0.f) ? o0 : (__expf(o0) - 1.0f);
    o1 = (o1 > 0.f) ? o1 : (__expf(o1) - 1.0f);
    o2 = (o2 > 0.f) ? o2 : (__expf(o2) - 1.0f);
    o3 = (o3 > 0.f) ? o3 : (__expf(o3) - 1.0f);
    ushort4 ob; ob.x = f2bf(o0); ob.y = f2bf(o1); ob.z = f2bf(o2); ob.w = f2bf(o3);
    *(ushort4*)&out[(size_t)n * 256 + lane * 4] = ob;
}

// agg2: 8 nodes/block, one half-wave per node (128-B row across 32 lanes).
// Same two-phase staged-gather structure as agg1. (R1-exact)
__global__ __launch_bounds__(256) void agg2_kernel(const ushort* __restrict__ h,
                                                   const float* __restrict__ als,
                                                   const float* __restrict__ ald,
                                                   const int* __restrict__ indptr,
                                                   const int* __restrict__ csr_src,
                                                   const float* __restrict__ bias,
                                                   float* __restrict__ out, int N) {
    __shared__ int   s_s[8][32];
    __shared__ float s_w[8][32];
    int tid = threadIdx.x;
    int sl  = tid >> 5;        // half-wave slice 0..7
    int l32 = tid & 31;
    int n = blockIdx.x * 8 + sl;
    if (n >= N) return;
    int beg = indptr[n], end = indptr[n + 1];
    float ald_n = ald[n];

    float2 acc = make_float2(0.f, 0.f);
    float den = 0.f;

    for (int base = beg; base < end; base += 32) {
        int cnt = end - base; if (cnt > 32) cnt = 32;
        if (l32 < cnt) {
            int s = csr_src[base + l32];
            s_s[sl][l32] = s;
            s_w[sl][l32] = edge_w(als[s] + ald_n);
        }
        #pragma unroll 4
        for (int e = 0; e < cnt; ++e) {
            int s = s_s[sl][e];
            float wt = s_w[sl][e];
            ushort2 hv = *(const ushort2*)&h[(size_t)s * 64 + l32 * 2];
            acc.x = fmaf(wt, bf2f(hv.x), acc.x);
            acc.y = fmaf(wt, bf2f(hv.y), acc.y);
            den += wt;
        }
    }

    float inv = 1.0f / den;
    float o0 = acc.x * inv + bias[l32 * 2];
    float o1 = acc.y * inv + bias[l32 * 2 + 1];
    o0 = (o0 > 0.f) ? o0 : (__expf(o0) - 1.0f);
    o1 = (o1 > 0.f) ? o1 : (__expf(o1) - 1.0f);
    *(float2*)&out[(size_t)n * 64 + l32 * 2] = make_float2(o0, o1);
}

// Fused mean-pool + FC: one block per graph (batch sorted => contiguous range).
__global__ __launch_bounds__(256) void pool_fc_kernel(const float* __restrict__ hfin,
                                                      const int* __restrict__ batch,
                                                      const float* __restrict__ fc_w,
                                                      const float* __restrict__ fc_b,
                                                      float* __restrict__ out, int N) {
    __shared__ float lacc[4][64];
    int g = blockIdx.x;
    int beg, end;
    {
        int lo = 0, hi = N;
        while (lo < hi) { int mid = (lo + hi) >> 1; if (batch[mid] < g) lo = mid + 1; else hi = mid; }
        beg = lo;
        lo = beg; hi = N;
        while (lo < hi) { int mid = (lo + hi) >> 1; if (batch[mid] < g + 1) lo = mid + 1; else hi = mid; }
        end = lo;
    }
    int lane = threadIdx.x & 63;
    int wv = threadIdx.x >> 6;
    float acc = 0.f;
    for (int n = beg + wv; n < end; n += 4)
        acc += hfin[(size_t)n * 64 + lane];
    lacc[wv][lane] = acc;
    __syncthreads();
    if (wv == 0) {
        float s = lacc[0][lane] + lacc[1][lane] + lacc[2][lane] + lacc[3][lane];
        float cnt = fmaxf((float)(end - beg), 1.0f);
        float pooled = s / cnt;
        float p0 = wave_reduce_sum(pooled * fc_w[lane * 2 + 0]);
        float p1 = wave_reduce_sum(pooled * fc_w[lane * 2 + 1]);
        if (lane == 0) {
            out[g * 2 + 0] = p0 + fc_b[0];
            out[g * 2 + 1] = p1 + fc_b[1];
        }
    }
}

// ---------------------------------------------------------------------------
extern "C" void kernel_launch(void* const* d_in, const int* in_sizes, int n_in,
                              void* d_out, int out_size, void* d_ws, size_t ws_size,
                              hipStream_t stream) {
    const float* x      = (const float*)d_in[0];
    const int*   ei     = (const int*)d_in[1];
    const int*   batch  = (const int*)d_in[2];
    const float* W1     = (const float*)d_in[3];
    const float* asrc1  = (const float*)d_in[4];
    const float* adst1  = (const float*)d_in[5];
    const float* b1     = (const float*)d_in[6];
    const float* W2     = (const float*)d_in[7];
    const float* asrc2  = (const float*)d_in[8];
    const float* adst2  = (const float*)d_in[9];
    const float* b2     = (const float*)d_in[10];
    const float* fc_w   = (const float*)d_in[11];
    const float* fc_b   = (const float*)d_in[12];
    float* out          = (float*)d_out;

    const int N = in_sizes[2];          // 50000
    const int E = in_sizes[1] / 2;      // 850000
    const int* src = ei;
    const int* dst = ei + E;

    float* ws = (float*)d_ws;
    int*    counts  = (int*)(ws + WS_COUNTS);
    int*    indptr  = (int*)(ws + WS_INDPTR);
    int*    cursor  = (int*)(ws + WS_CURSOR);
    int*    csr_src = (int*)(ws + WS_CSRSRC);
    int*    bsum    = (int*)(ws + WS_BSUM);
    float*  al_s1   = ws + WS_ALS1;
    float*  al_d1   = ws + WS_ALD1;
    float*  al_s2   = ws + WS_ALS2;
    float*  al_d2   = ws + WS_ALD2;
    ushort* bp      = (ushort*)(ws + WS_BP);
    ushort* bp2     = (ushort*)(ws + WS_BP2);
    ushort* h1b     = (ushort*)(ws + WS_H1B);
    ushort* x2b     = (ushort*)(ws + WS_X2B);
    ushort* h2b     = (ushort*)(ws + WS_H2B);
    float*  hfin    = ws + WS_HFIN;
    ushort* xb      = (ushort*)(ws + WS_XB);

    const int nb = (N + 1023) / 1024;   // scan blocks (<=64)

    // 1. fused prelude: pack weights + zero counts; stream x -> bf16
    prep_kernel<<<1284, 256, 0, stream>>>(W1, W2, bp, bp2, counts);
    cvt_x_kernel<<<2048, 256, 0, stream>>>(x, xb, (long)N * (INDIM / 8));
    // 2. CSR build (by dst)
    hist_kernel<<<(E + 255) / 256, 256, 0, stream>>>(dst, counts, E);
    scan1_kernel<<<nb, 1024, 0, stream>>>(counts, indptr, bsum, N);
    scan2_kernel<<<1, 64, 0, stream>>>(bsum, nb);
    scan3_kernel<<<nb, 1024, 0, stream>>>(counts, indptr, cursor, bsum, N);
    fill_kernel<<<(E + 255) / 256, 256, 0, stream>>>(src, dst, cursor, csr_src, E);
    // 3. layer 1 GEMM (direct register-fragment, no LDS/barriers) -> h1b + logits
    gemm1_mfma<<<(N + 127) / 128, 256, 0, stream>>>(
        xb, bp, h1b, asrc1, adst1, al_s1, al_d1, N);
    // 4. aggregate (inline softmax weights) + bias + ELU -> x2b (bf16)
    agg1_kernel<<<(N + 3) / 4, 256, 0, stream>>>(h1b, al_s1, al_d1, indptr, csr_src, b1, x2b, N);
    // 5. layer 2 GEMM -> h2b (bf16) + fused att logits
    gemm2_mfma<<<(N + 127) / 128, 256, 0, stream>>>(
        x2b, bp2, h2b, asrc2, adst2, al_s2, al_d2, N);
    // 6. aggregate (inline softmax weights) + bias + ELU -> hfin (fp32)
    agg2_kernel<<<(N + 7) / 8, 256, 0, stream>>>(h2b, al_s2, al_d2, indptr, csr_src, b2, hfin, N);
    // 7. fused mean pool + FC
    pool_fc_kernel<<<NGRAPHS, 256, 0, stream>>>(hfin, batch, fc_w, fc_b, out, N);
}

// Round 9
// 582.686 us; speedup vs baseline: 1.1921x; 1.1921x over previous
//
#include <hip/hip_runtime.h>
#include <hip/hip_bf16.h>

// Problem constants (fixed by the reference setup)
#define NNODES   50000
#define NGRAPHS  64
#define INDIM    1024
#define HIDC     64      // channels per head
#define HEADS1   4
#define F1       (HEADS1*HIDC)   // 256
#define NEG_SLOPE 0.2f

// ---------------------------------------------------------------------------
// Workspace layout (4-byte words). All vector-accessed buffers 16B-aligned.
#define WS_COUNTS   0                    // int[50000]
#define WS_ZEROLEN  50000                // words to zero (counts only)
#define WS_INDPTR   54208                // int[50001]
#define WS_CURSOR   104256               // int[50000]
#define WS_CSRSRC   154304               // int[850000]
#define WS_CSRDST   1004304              // (dead - kept for layout stability)
#define WS_BSUM     1854304              // int[64]
#define WS_ALS1     1854368              // float[200000]
#define WS_ALD1     2054368              // float[200000]
#define WS_ALS2     2254368              // float[50000]
#define WS_ALD2     2304368              // float[50000]
#define WS_BP       2354368              // ushort[262144] (packed bf16 W1)
#define WS_BP2      2485440              // ushort[16384]  (packed bf16 W2)
#define WS_H1B      2493632              // ushort[12,800,000] bf16 h1
#define WS_X2B      8893632              // ushort[12,800,000] bf16 x2
#define WS_H2B      15293632             // ushort[3,200,000]  bf16 h2
#define WS_HFIN     16893632             // float[3,200,000]

typedef __attribute__((ext_vector_type(8))) short bf16x8;
typedef __attribute__((ext_vector_type(4))) float f32x4;

__device__ __forceinline__ ushort f2bf(float f) {
    union { float f; uint u; } v; v.f = f;
    uint r = v.u + 0x7fff + ((v.u >> 16) & 1);   // round-to-nearest-even
    return (ushort)(r >> 16);
}
__device__ __forceinline__ float bf2f(ushort u) {
    union { uint u; float f; } v; v.u = (uint)u << 16; return v.f;
}

// ---------------------------------------------------------------------------
// Fused prelude: pack W1 + pack W2 into bf16 MFMA-B fragment order, zero counts.
// blocks [0,1024): W1, [1024,1088): W2, [1088,1284): zero counts.
__global__ void prep_kernel(const float* __restrict__ W1, const float* __restrict__ W2,
                            ushort* __restrict__ Bp1, ushort* __restrict__ Bp2,
                            int* __restrict__ counts) {
    int b = blockIdx.x;
    int tid = threadIdx.x;
    if (b < 1024) {                      // pack W1 [1024,256]
        int o = b * 256 + tid;           // 0 .. 262143
        int j = o & 7;
        int lane = (o >> 3) & 63;
        int kchunk = (o >> 9) & 31;
        int ntile = o >> 14;
        int k = kchunk * 32 + (lane >> 4) * 8 + j;
        int n = ntile * 16 + (lane & 15);
        Bp1[o] = f2bf(W1[k * 256 + n]);
    } else if (b < 1088) {               // pack W2 [256,64]
        int o = (b - 1024) * 256 + tid;  // 0 .. 16383
        int j = o & 7;
        int lane = (o >> 3) & 63;
        int kchunk = (o >> 9) & 7;
        int ntile = o >> 12;
        int k = kchunk * 32 + (lane >> 4) * 8 + j;
        int n = ntile * 16 + (lane & 15);
        Bp2[o] = f2bf(W2[k * 64 + n]);
    } else {                             // zero counts
        int i = (b - 1088) * 256 + tid;
        if (i < NNODES) counts[i] = 0;
    }
}

__global__ void hist_kernel(const int* __restrict__ dst, int* __restrict__ counts, int E) {
    int i = blockIdx.x * blockDim.x + threadIdx.x;
    if (i < E) atomicAdd(&counts[dst[i]], 1);
}

// --- 3-kernel multi-block scan -------------------------------------------
__global__ __launch_bounds__(1024) void scan1_kernel(const int* __restrict__ counts,
                                                     int* __restrict__ indptr,
                                                     int* __restrict__ bsum, int N) {
    __shared__ int sm[1024];
    int b = blockIdx.x;
    int i = b * 1024 + (int)threadIdx.x;
    int v = (i < N) ? counts[i] : 0;
    sm[threadIdx.x] = v;
    __syncthreads();
    for (int off = 1; off < 1024; off <<= 1) {
        int t = (threadIdx.x >= (unsigned)off) ? sm[threadIdx.x - off] : 0;
        __syncthreads();
        sm[threadIdx.x] += t;
        __syncthreads();
    }
    if (i < N) indptr[i + 1] = sm[threadIdx.x];
    if (threadIdx.x == 1023) bsum[b] = sm[1023];
}

__global__ void scan2_kernel(int* __restrict__ bsum, int nb) {
    int lane = threadIdx.x;
    int v = (lane < nb) ? bsum[lane] : 0;
    int orig = v;
    #pragma unroll
    for (int off = 1; off < 64; off <<= 1) {
        int t = __shfl_up(v, off, 64);
        if (lane >= off) v += t;
    }
    if (lane < nb) bsum[lane] = v - orig;   // exclusive
}

__global__ __launch_bounds__(1024) void scan3_kernel(const int* __restrict__ counts,
                                                     int* __restrict__ indptr,
                                                     int* __restrict__ cursor,
                                                     const int* __restrict__ bsum, int N) {
    int i = blockIdx.x * 1024 + (int)threadIdx.x;
    if (i == 0) indptr[0] = 0;
    if (i < N) {
        int incl = indptr[i + 1] + bsum[blockIdx.x];
        indptr[i + 1] = incl;
        cursor[i] = incl - counts[i];
    }
}

// csr_dst was dead (never read) -> removed; only csr_src is built.
__global__ void fill_kernel(const int* __restrict__ src, const int* __restrict__ dst,
                            int* __restrict__ cursor, int* __restrict__ csr_src, int E) {
    int i = blockIdx.x * blockDim.x + threadIdx.x;
    if (i < E) {
        int d = dst[i];
        int pos = atomicAdd(&cursor[d], 1);
        csr_src[pos] = src[i];
    }
}

// ---------------------------------------------------------------------------
// bf16 MFMA GEMM, layer 1: h1b[M,256](bf16) = A[M,1024](fp32) @ W1.
// R1-EXACT (best measured gemm1: 128.6-129 us; VGPR 124): tile 128x256 (FULL
// N per block -> A staged exactly once), double-buffered 8KB bf16 LDS;
// register prefetch issued AFTER the barrier. Epilogue fuses att logits.
__global__ __launch_bounds__(256) void gemm1_mfma(const float* __restrict__ A,
                                                  const ushort* __restrict__ Bp,
                                                  ushort* __restrict__ C,
                                                  const float* __restrict__ asrc,
                                                  const float* __restrict__ adst,
                                                  float* __restrict__ als,
                                                  float* __restrict__ ald,
                                                  int M) {
    __shared__ __align__(16) ushort Atile[2][128 * 32];   // 2 x 8 KB
    const int K = 1024, N = 256;
    int tid = threadIdx.x;
    int lane = tid & 63;
    int w = tid >> 6;
    int wm = w >> 1, wn = w & 1;          // wave covers 64 rows x 128 cols
    int m0 = blockIdx.x * 128;

    const float* srow[4];
    int soff[4];
    #pragma unroll
    for (int l = 0; l < 4; ++l) {
        int slot = l * 256 + tid;
        int m = slot >> 3, hc = slot & 7;
        int c = hc >> 1;
        int row = m0 + m; if (row >= M) row = M - 1;
        srow[l] = A + (size_t)row * K + hc * 4;
        soff[l] = (m * 4 + (c ^ ((m >> 1) & 3))) * 8 + (hc & 1) * 4;
    }
    int afrag_off[4];
    #pragma unroll
    for (int mt = 0; mt < 4; ++mt) {
        int r = wm * 64 + mt * 16 + (lane & 15);
        int cq = lane >> 4;
        afrag_off[mt] = (r * 4 + (cq ^ ((r >> 1) & 3))) * 8;
    }
    const ushort* bbase[8];
    #pragma unroll
    for (int nt = 0; nt < 8; ++nt) {
        int ntile = wn * 8 + nt;
        bbase[nt] = Bp + ((size_t)(ntile * 32) * 64 + lane) * 8;
    }

    f32x4 acc[4][8] = {};
    float4 v[4];
    #pragma unroll
    for (int l = 0; l < 4; ++l) v[l] = *(const float4*)(srow[l]);

    for (int kc = 0; kc < 32; ++kc) {
        ushort* At = Atile[kc & 1];
        #pragma unroll
        for (int l = 0; l < 4; ++l) {
            ushort4 b;
            b.x = f2bf(v[l].x); b.y = f2bf(v[l].y);
            b.z = f2bf(v[l].z); b.w = f2bf(v[l].w);
            *(ushort4*)&At[soff[l]] = b;
        }
        __syncthreads();
        // prefetch next A chunk AFTER the barrier: in flight during MFMAs
        if (kc < 31) {
            #pragma unroll
            for (int l = 0; l < 4; ++l)
                v[l] = *(const float4*)(srow[l] + (kc + 1) * 32);
        }
        bf16x8 afr[4];
        #pragma unroll
        for (int mt = 0; mt < 4; ++mt)
            afr[mt] = *(const bf16x8*)&At[afrag_off[mt]];
        #pragma unroll
        for (int nt = 0; nt < 8; ++nt) {
            bf16x8 bfr = *(const bf16x8*)(bbase[nt] + (size_t)kc * 64 * 8);
            #pragma unroll
            for (int mt = 0; mt < 4; ++mt)
                acc[mt][nt] = __builtin_amdgcn_mfma_f32_16x16x32_bf16(afr[mt], bfr, acc[mt][nt], 0, 0, 0);
        }
    }

    // epilogue: C write (bf16) + fused attention logits (2 heads per wave)
    float a_s[8], a_d[8];
    #pragma unroll
    for (int nt = 0; nt < 8; ++nt) {
        int col = wn * 128 + nt * 16 + (lane & 15);   // head = col>>6
        a_s[nt] = asrc[col];
        a_d[nt] = adst[col];
    }
    #pragma unroll
    for (int mt = 0; mt < 4; ++mt) {
        #pragma unroll
        for (int nt = 0; nt < 8; ++nt) {
            int col = wn * 128 + nt * 16 + (lane & 15);
            #pragma unroll
            for (int r = 0; r < 4; ++r) {
                int row = m0 + wm * 64 + mt * 16 + (lane >> 4) * 4 + r;
                if (row < M) C[(size_t)row * N + col] = f2bf(acc[mt][nt][r]);
            }
        }
        #pragma unroll
        for (int hg = 0; hg < 2; ++hg) {         // head group: nt 4hg..4hg+3
            int head = wn * 2 + hg;
            #pragma unroll
            for (int r = 0; r < 4; ++r) {
                int row = m0 + wm * 64 + mt * 16 + (lane >> 4) * 4 + r;
                float s = 0.f, d = 0.f;
                #pragma unroll
                for (int q = 0; q < 4; ++q) {
                    float c = acc[mt][4 * hg + q][r];
                    s = fmaf(c, a_s[4 * hg + q], s);
                    d = fmaf(c, a_d[4 * hg + q], d);
                }
                #pragma unroll
                for (int off = 1; off < 16; off <<= 1) {
                    s += __shfl_xor(s, off, 64);
                    d += __shfl_xor(d, off, 64);
                }
                if ((lane & 15) == 0 && row < M) {
                    als[row * 4 + head] = s;
                    ald[row * 4 + head] = d;
                }
            }
        }
    }
}

// ---------------------------------------------------------------------------
// bf16 MFMA GEMM, layer 2: h2b[M,64](bf16) = x2b[M,256](bf16) @ W2. (R1-exact)
__global__ __launch_bounds__(256) void gemm2_mfma(const ushort* __restrict__ Ab,
                                                  const ushort* __restrict__ Bp,
                                                  ushort* __restrict__ C,
                                                  const float* __restrict__ asrc,
                                                  const float* __restrict__ adst,
                                                  float* __restrict__ als,
                                                  float* __restrict__ ald,
                                                  int M) {
    int tid = threadIdx.x;
    int lane = tid & 63;
    int w = tid >> 6;
    int m0 = blockIdx.x * 128 + w * 32;

    f32x4 acc[2][4] = {};
    #pragma unroll 2
    for (int kc = 0; kc < 8; ++kc) {
        bf16x8 afr[2];
        #pragma unroll
        for (int mt = 0; mt < 2; ++mt) {
            int r = m0 + mt * 16 + (lane & 15);
            if (r >= M) r = M - 1;
            afr[mt] = *(const bf16x8*)&Ab[(size_t)r * 256 + kc * 32 + (lane >> 4) * 8];
        }
        #pragma unroll
        for (int nt = 0; nt < 4; ++nt) {
            bf16x8 bfr = *(const bf16x8*)&Bp[((nt * 8 + kc) * 64 + lane) * 8];
            acc[0][nt] = __builtin_amdgcn_mfma_f32_16x16x32_bf16(afr[0], bfr, acc[0][nt], 0, 0, 0);
            acc[1][nt] = __builtin_amdgcn_mfma_f32_16x16x32_bf16(afr[1], bfr, acc[1][nt], 0, 0, 0);
        }
    }
    float a_s[4], a_d[4];
    #pragma unroll
    for (int nt = 0; nt < 4; ++nt) {
        a_s[nt] = asrc[nt * 16 + (lane & 15)];
        a_d[nt] = adst[nt * 16 + (lane & 15)];
    }
    #pragma unroll
    for (int mt = 0; mt < 2; ++mt) {
        #pragma unroll
        for (int nt = 0; nt < 4; ++nt) {
            int col = nt * 16 + (lane & 15);
            #pragma unroll
            for (int r = 0; r < 4; ++r) {
                int row = m0 + mt * 16 + (lane >> 4) * 4 + r;
                if (row < M) C[(size_t)row * 64 + col] = f2bf(acc[mt][nt][r]);
            }
        }
        #pragma unroll
        for (int r = 0; r < 4; ++r) {
            int row = m0 + mt * 16 + (lane >> 4) * 4 + r;
            float s = 0.f, d = 0.f;
            #pragma unroll
            for (int nt = 0; nt < 4; ++nt) {
                float c = acc[mt][nt][r];
                s = fmaf(c, a_s[nt], s);
                d = fmaf(c, a_d[nt], d);
            }
            #pragma unroll
            for (int off = 1; off < 16; off <<= 1) {
                s += __shfl_xor(s, off, 64);
                d += __shfl_xor(d, off, 64);
            }
            if ((lane & 15) == 0 && row < M) {
                als[row] = s;
                ald[row] = d;
            }
        }
    }
}

// ---------------------------------------------------------------------------
__device__ __forceinline__ float wave_reduce_sum(float v) {
    #pragma unroll
    for (int off = 32; off > 0; off >>= 1) v += __shfl_xor(v, off, 64);
    return v;
}

__device__ __forceinline__ float edge_w(float e) {
    e = (e > 0.f) ? e : NEG_SLOPE * e;
    return __expf(e);
}

// agg1 v2: 4 nodes/block, one wave per node. HALF-WAVE per edge: 32 lanes x
// 16B (uint4) cover the 512B row; the two half-waves process interleaved edge
// parities (e%2==sub; balanced for avg deg 17). 2 rows/iter, 8 rows in flight
// at unroll 4 -- 2x the MLP of v1 at half the issue count. Cross-parity
// combine = one shfl_xor(32) per channel at the end. No __syncthreads.
__global__ __launch_bounds__(256) void agg1_kernel(const ushort* __restrict__ h,
                                                   const float* __restrict__ als,
                                                   const float* __restrict__ ald,
                                                   const int* __restrict__ indptr,
                                                   const int* __restrict__ csr_src,
                                                   const float* __restrict__ bias,
                                                   ushort* __restrict__ out, int N) {
    __shared__ int   s_s[4][64];
    __shared__ float s_w[4][64][4];
    int wv   = threadIdx.x >> 6;
    int lane = threadIdx.x & 63;
    int n = blockIdx.x * 4 + wv;
    if (n >= N) return;
    int sub = lane >> 5;          // edge parity 0/1
    int l32 = lane & 31;          // channel group: ch = l32*8 .. +7
    int hd  = l32 >> 3;           // head of these 8 channels
    int beg = indptr[n], end = indptr[n + 1];
    float4 aldv = *(const float4*)&ald[n * 4];

    float acc[8] = {};
    float den = 0.f;

    for (int base = beg; base < end; base += 64) {
        int cnt = end - base; if (cnt > 64) cnt = 64;
        if (lane < cnt) {
            int s = csr_src[base + lane];
            s_s[wv][lane] = s;
            float4 av = *(const float4*)&als[s * 4];
            s_w[wv][lane][0] = edge_w(av.x + aldv.x);
            s_w[wv][lane][1] = edge_w(av.y + aldv.y);
            s_w[wv][lane][2] = edge_w(av.z + aldv.z);
            s_w[wv][lane][3] = edge_w(av.w + aldv.w);
        }
        // wave-private LDS, lock-step wave: no barrier needed
        #pragma unroll 4
        for (int e = sub; e < cnt; e += 2) {
            int s = s_s[wv][e];
            float wt = s_w[wv][e][hd];
            uint4 hv = *(const uint4*)&h[(size_t)s * 256 + l32 * 8];
            acc[0] = fmaf(wt, bf2f((ushort)(hv.x & 0xffff)), acc[0]);
            acc[1] = fmaf(wt, bf2f((ushort)(hv.x >> 16)),    acc[1]);
            acc[2] = fmaf(wt, bf2f((ushort)(hv.y & 0xffff)), acc[2]);
            acc[3] = fmaf(wt, bf2f((ushort)(hv.y >> 16)),    acc[3]);
            acc[4] = fmaf(wt, bf2f((ushort)(hv.z & 0xffff)), acc[4]);
            acc[5] = fmaf(wt, bf2f((ushort)(hv.z >> 16)),    acc[5]);
            acc[6] = fmaf(wt, bf2f((ushort)(hv.w & 0xffff)), acc[6]);
            acc[7] = fmaf(wt, bf2f((ushort)(hv.w >> 16)),    acc[7]);
            den += wt;
        }
    }

    // combine the two edge parities (lanes l32 and l32+32 hold same channels)
    #pragma unroll
    for (int j = 0; j < 8; ++j) acc[j] += __shfl_xor(acc[j], 32, 64);
    den += __shfl_xor(den, 32, 64);

    if (sub == 0) {
        float inv = 1.0f / den;
        const float4* bp4 = (const float4*)&bias[l32 * 8];
        float4 b0 = bp4[0], b1 = bp4[1];
        float o[8];
        o[0] = acc[0] * inv + b0.x; o[1] = acc[1] * inv + b0.y;
        o[2] = acc[2] * inv + b0.z; o[3] = acc[3] * inv + b0.w;
        o[4] = acc[4] * inv + b1.x; o[5] = acc[5] * inv + b1.y;
        o[6] = acc[6] * inv + b1.z; o[7] = acc[7] * inv + b1.w;
        #pragma unroll
        for (int j = 0; j < 8; ++j)
            o[j] = (o[j] > 0.f) ? o[j] : (__expf(o[j]) - 1.0f);
        uint4 ob;
        ob.x = (uint)f2bf(o[0]) | ((uint)f2bf(o[1]) << 16);
        ob.y = (uint)f2bf(o[2]) | ((uint)f2bf(o[3]) << 16);
        ob.z = (uint)f2bf(o[4]) | ((uint)f2bf(o[5]) << 16);
        ob.w = (uint)f2bf(o[6]) | ((uint)f2bf(o[7]) << 16);
        *(uint4*)&out[(size_t)n * 256 + l32 * 8] = ob;
    }
}

// agg2 v2: 4 nodes/block, one wave per node. QUARTER-WAVE per edge: 16 lanes
// x 8B (uint2) cover the 128B row; 4 interleaved edge parities -> 4 rows/iter,
// 16 in flight at unroll 4. Combine = shfl_xor(16)+shfl_xor(32).
__global__ __launch_bounds__(256) void agg2_kernel(const ushort* __restrict__ h,
                                                   const float* __restrict__ als,
                                                   const float* __restrict__ ald,
                                                   const int* __restrict__ indptr,
                                                   const int* __restrict__ csr_src,
                                                   const float* __restrict__ bias,
                                                   float* __restrict__ out, int N) {
    __shared__ int   s_s[4][64];
    __shared__ float s_w[4][64];
    int wv   = threadIdx.x >> 6;
    int lane = threadIdx.x & 63;
    int n = blockIdx.x * 4 + wv;
    if (n >= N) return;
    int sub = lane >> 4;          // edge parity 0..3
    int l16 = lane & 15;          // channel group: ch = l16*4 .. +3
    int beg = indptr[n], end = indptr[n + 1];
    float ald_n = ald[n];

    float acc[4] = {};
    float den = 0.f;

    for (int base = beg; base < end; base += 64) {
        int cnt = end - base; if (cnt > 64) cnt = 64;
        if (lane < cnt) {
            int s = csr_src[base + lane];
            s_s[wv][lane] = s;
            s_w[wv][lane] = edge_w(als[s] + ald_n);
        }
        #pragma unroll 4
        for (int e = sub; e < cnt; e += 4) {
            int s = s_s[wv][e];
            float wt = s_w[wv][e];
            uint2 hv = *(const uint2*)&h[(size_t)s * 64 + l16 * 4];
            acc[0] = fmaf(wt, bf2f((ushort)(hv.x & 0xffff)), acc[0]);
            acc[1] = fmaf(wt, bf2f((ushort)(hv.x >> 16)),    acc[1]);
            acc[2] = fmaf(wt, bf2f((ushort)(hv.y & 0xffff)), acc[2]);
            acc[3] = fmaf(wt, bf2f((ushort)(hv.y >> 16)),    acc[3]);
            den += wt;
        }
    }

    #pragma unroll
    for (int j = 0; j < 4; ++j) {
        acc[j] += __shfl_xor(acc[j], 16, 64);
        acc[j] += __shfl_xor(acc[j], 32, 64);
    }
    den += __shfl_xor(den, 16, 64);
    den += __shfl_xor(den, 32, 64);

    if (sub == 0) {
        float inv = 1.0f / den;
        float o0 = acc[0] * inv + bias[l16 * 4 + 0];
        float o1 = acc[1] * inv + bias[l16 * 4 + 1];
        float o2 = acc[2] * inv + bias[l16 * 4 + 2];
        float o3 = acc[3] * inv + bias[l16 * 4 + 3];
        o0 = (o0 > 0.f) ? o0 : (__expf(o0) - 1.0f);
        o1 = (o1 > 0.f) ? o1 : (__expf(o1) - 1.0f);
        o2 = (o2 > 0.f) ? o2 : (__expf(o2) - 1.0f);
        o3 = (o3 > 0.f) ? o3 : (__expf(o3) - 1.0f);
        *(float4*)&out[(size_t)n * 64 + l16 * 4] = make_float4(o0, o1, o2, o3);
    }
}

// Fused mean-pool + FC: one block per graph (batch sorted => contiguous range).
__global__ __launch_bounds__(256) void pool_fc_kernel(const float* __restrict__ hfin,
                                                      const int* __restrict__ batch,
                                                      const float* __restrict__ fc_w,
                                                      const float* __restrict__ fc_b,
                                                      float* __restrict__ out, int N) {
    __shared__ float lacc[4][64];
    int g = blockIdx.x;
    int beg, end;
    {
        int lo = 0, hi = N;
        while (lo < hi) { int mid = (lo + hi) >> 1; if (batch[mid] < g) lo = mid + 1; else hi = mid; }
        beg = lo;
        lo = beg; hi = N;
        while (lo < hi) { int mid = (lo + hi) >> 1; if (batch[mid] < g + 1) lo = mid + 1; else hi = mid; }
        end = lo;
    }
    int lane = threadIdx.x & 63;
    int wv = threadIdx.x >> 6;
    float acc = 0.f;
    for (int n = beg + wv; n < end; n += 4)
        acc += hfin[(size_t)n * 64 + lane];
    lacc[wv][lane] = acc;
    __syncthreads();
    if (wv == 0) {
        float s = lacc[0][lane] + lacc[1][lane] + lacc[2][lane] + lacc[3][lane];
        float cnt = fmaxf((float)(end - beg), 1.0f);
        float pooled = s / cnt;
        float p0 = wave_reduce_sum(pooled * fc_w[lane * 2 + 0]);
        float p1 = wave_reduce_sum(pooled * fc_w[lane * 2 + 1]);
        if (lane == 0) {
            out[g * 2 + 0] = p0 + fc_b[0];
            out[g * 2 + 1] = p1 + fc_b[1];
        }
    }
}

// ---------------------------------------------------------------------------
extern "C" void kernel_launch(void* const* d_in, const int* in_sizes, int n_in,
                              void* d_out, int out_size, void* d_ws, size_t ws_size,
                              hipStream_t stream) {
    const float* x      = (const float*)d_in[0];
    const int*   ei     = (const int*)d_in[1];
    const int*   batch  = (const int*)d_in[2];
    const float* W1     = (const float*)d_in[3];
    const float* asrc1  = (const float*)d_in[4];
    const float* adst1  = (const float*)d_in[5];
    const float* b1     = (const float*)d_in[6];
    const float* W2     = (const float*)d_in[7];
    const float* asrc2  = (const float*)d_in[8];
    const float* adst2  = (const float*)d_in[9];
    const float* b2     = (const float*)d_in[10];
    const float* fc_w   = (const float*)d_in[11];
    const float* fc_b   = (const float*)d_in[12];
    float* out          = (float*)d_out;

    const int N = in_sizes[2];          // 50000
    const int E = in_sizes[1] / 2;      // 850000
    const int* src = ei;
    const int* dst = ei + E;

    float* ws = (float*)d_ws;
    int*    counts  = (int*)(ws + WS_COUNTS);
    int*    indptr  = (int*)(ws + WS_INDPTR);
    int*    cursor  = (int*)(ws + WS_CURSOR);
    int*    csr_src = (int*)(ws + WS_CSRSRC);
    int*    bsum    = (int*)(ws + WS_BSUM);
    float*  al_s1   = ws + WS_ALS1;
    float*  al_d1   = ws + WS_ALD1;
    float*  al_s2   = ws + WS_ALS2;
    float*  al_d2   = ws + WS_ALD2;
    ushort* bp      = (ushort*)(ws + WS_BP);
    ushort* bp2     = (ushort*)(ws + WS_BP2);
    ushort* h1b     = (ushort*)(ws + WS_H1B);
    ushort* x2b     = (ushort*)(ws + WS_X2B);
    ushort* h2b     = (ushort*)(ws + WS_H2B);
    float*  hfin    = ws + WS_HFIN;

    const int nb = (N + 1023) / 1024;   // scan blocks (<=64)

    // 1. fused prelude: pack weights + zero counts (1024 + 64 + 196 blocks)
    prep_kernel<<<1284, 256, 0, stream>>>(W1, W2, bp, bp2, counts);
    // 2. CSR build (by dst)
    hist_kernel<<<(E + 255) / 256, 256, 0, stream>>>(dst, counts, E);
    scan1_kernel<<<nb, 1024, 0, stream>>>(counts, indptr, bsum, N);
    scan2_kernel<<<1, 64, 0, stream>>>(bsum, nb);
    scan3_kernel<<<nb, 1024, 0, stream>>>(counts, indptr, cursor, bsum, N);
    fill_kernel<<<(E + 255) / 256, 256, 0, stream>>>(src, dst, cursor, csr_src, E);
    // 3. layer 1 GEMM (R1-exact) -> h1b + fused att logits
    gemm1_mfma<<<(N + 127) / 128, 256, 0, stream>>>(
        x, bp, h1b, asrc1, adst1, al_s1, al_d1, N);
    // 4. aggregate (inline softmax weights) + bias + ELU -> x2b (bf16)
    agg1_kernel<<<(N + 3) / 4, 256, 0, stream>>>(h1b, al_s1, al_d1, indptr, csr_src, b1, x2b, N);
    // 5. layer 2 GEMM -> h2b (bf16) + fused att logits
    gemm2_mfma<<<(N + 127) / 128, 256, 0, stream>>>(
        x2b, bp2, h2b, asrc2, adst2, al_s2, al_d2, N);
    // 6. aggregate (inline softmax weights) + bias + ELU -> hfin (fp32)
    agg2_kernel<<<(N + 3) / 4, 256, 0, stream>>>(h2b, al_s2, al_d2, indptr, csr_src, b2, hfin, N);
    // 7. fused mean pool + FC
    pool_fc_kernel<<<NGRAPHS, 256, 0, stream>>>(hfin, batch, fc_w, fc_b, out, N);
}

// Round 10
// 553.550 us; speedup vs baseline: 1.2548x; 1.0526x over previous
//
#include <hip/hip_runtime.h>
#include <hip/hip_bf16.h>

// Problem constants (fixed by the reference setup)
#define NNODES   50000
#define NGRAPHS  64
#define INDIM    1024
#define HIDC     64      // channels per head
#define HEADS1   4
#define F1       (HEADS1*HIDC)   // 256
#define NEG_SLOPE 0.2f

// ---------------------------------------------------------------------------
// Workspace layout (4-byte words). All vector-accessed buffers 16B-aligned.
#define WS_COUNTS   0                    // int[50000]
#define WS_INDPTR   54208                // int[50001]
#define WS_CURSOR   104256               // int[50000]
#define WS_CSRSRC   154304               // int[850000]
#define WS_BSUM     1854304              // int[64]
#define WS_ALS1     1854368              // float[200000]
#define WS_ALD1     2054368              // float[200000]
#define WS_ALS2     2254368              // float[50000]
#define WS_ALD2     2304368              // float[50000]
#define WS_BP       2354368              // ushort[262144] (packed bf16 W1)
#define WS_BP2      2485440              // ushort[16384]  (packed bf16 W2)
#define WS_H1B      2493632              // ushort[12,800,000] bf16 h1
#define WS_X2B      8893632              // ushort[12,800,000] bf16 x2
#define WS_H2B      15293632             // ushort[3,200,000]  bf16 h2
#define WS_HFIN     16893632             // float[3,200,000]

typedef __attribute__((ext_vector_type(8))) short bf16x8;
typedef __attribute__((ext_vector_type(4))) float f32x4;

__device__ __forceinline__ ushort f2bf(float f) {
    union { float f; uint u; } v; v.f = f;
    uint r = v.u + 0x7fff + ((v.u >> 16) & 1);   // round-to-nearest-even
    return (ushort)(r >> 16);
}
__device__ __forceinline__ float bf2f(ushort u) {
    union { uint u; float f; } v; v.u = (uint)u << 16; return v.f;
}

// ---------------------------------------------------------------------------
// Fused: pack W1 + pack W2 + hist. hist is independent of the packs and hides
// under the (uncoalesced) W1 pack instead of running alone.
// blocks [0,1024): W1, [1024,1088): W2, [1088..): hist.
__global__ void packhist_kernel(const float* __restrict__ W1, const float* __restrict__ W2,
                                ushort* __restrict__ Bp1, ushort* __restrict__ Bp2,
                                const int* __restrict__ dst, int* __restrict__ counts,
                                int E) {
    int b = blockIdx.x;
    int tid = threadIdx.x;
    if (b < 1024) {                      // pack W1 [1024,256]
        int o = b * 256 + tid;           // 0 .. 262143
        int j = o & 7;
        int lane = (o >> 3) & 63;
        int kchunk = (o >> 9) & 31;
        int ntile = o >> 14;
        int k = kchunk * 32 + (lane >> 4) * 8 + j;
        int n = ntile * 16 + (lane & 15);
        Bp1[o] = f2bf(W1[k * 256 + n]);
    } else if (b < 1088) {               // pack W2 [256,64]
        int o = (b - 1024) * 256 + tid;  // 0 .. 16383
        int j = o & 7;
        int lane = (o >> 3) & 63;
        int kchunk = (o >> 9) & 7;
        int ntile = o >> 12;
        int k = kchunk * 32 + (lane >> 4) * 8 + j;
        int n = ntile * 16 + (lane & 15);
        Bp2[o] = f2bf(W2[k * 64 + n]);
    } else {                             // histogram of dst
        int i = (b - 1088) * 256 + tid;
        if (i < E) atomicAdd(&counts[dst[i]], 1);
    }
}

// --- 3-kernel multi-block scan -------------------------------------------
__global__ __launch_bounds__(1024) void scan1_kernel(const int* __restrict__ counts,
                                                     int* __restrict__ indptr,
                                                     int* __restrict__ bsum, int N) {
    __shared__ int sm[1024];
    int b = blockIdx.x;
    int i = b * 1024 + (int)threadIdx.x;
    int v = (i < N) ? counts[i] : 0;
    sm[threadIdx.x] = v;
    __syncthreads();
    for (int off = 1; off < 1024; off <<= 1) {
        int t = (threadIdx.x >= (unsigned)off) ? sm[threadIdx.x - off] : 0;
        __syncthreads();
        sm[threadIdx.x] += t;
        __syncthreads();
    }
    if (i < N) indptr[i + 1] = sm[threadIdx.x];
    if (threadIdx.x == 1023) bsum[b] = sm[1023];
}

__global__ void scan2_kernel(int* __restrict__ bsum, int nb) {
    int lane = threadIdx.x;
    int v = (lane < nb) ? bsum[lane] : 0;
    int orig = v;
    #pragma unroll
    for (int off = 1; off < 64; off <<= 1) {
        int t = __shfl_up(v, off, 64);
        if (lane >= off) v += t;
    }
    if (lane < nb) bsum[lane] = v - orig;   // exclusive
}

__global__ __launch_bounds__(1024) void scan3_kernel(const int* __restrict__ counts,
                                                     int* __restrict__ indptr,
                                                     int* __restrict__ cursor,
                                                     const int* __restrict__ bsum, int N) {
    int i = blockIdx.x * 1024 + (int)threadIdx.x;
    if (i == 0) indptr[0] = 0;
    if (i < N) {
        int incl = indptr[i + 1] + bsum[blockIdx.x];
        indptr[i + 1] = incl;
        cursor[i] = incl - counts[i];
    }
}

// ---------------------------------------------------------------------------
// Fused gemm1 + fill co-launch. Blocks [0,ng1): gemm1 (R9-exact, best
// measured 121 us); blocks [ng1..): CSR fill (random atomic scatter) -- it
// rides gemm1's idle memory pipes instead of running alone.
__global__ __launch_bounds__(256) void gemm1_fill(const float* __restrict__ A,
                                                  const ushort* __restrict__ Bp,
                                                  ushort* __restrict__ C,
                                                  const float* __restrict__ asrc,
                                                  const float* __restrict__ adst,
                                                  float* __restrict__ als,
                                                  float* __restrict__ ald,
                                                  int M, int ng1,
                                                  const int* __restrict__ src,
                                                  const int* __restrict__ dst,
                                                  int* __restrict__ cursor,
                                                  int* __restrict__ csr_src, int E) {
    __shared__ __align__(16) ushort Atile[2][128 * 32];   // 2 x 8 KB
    if (blockIdx.x >= (unsigned)ng1) {
        // ---- fill part ----
        int i = (blockIdx.x - ng1) * 256 + threadIdx.x;
        if (i < E) {
            int d = dst[i];
            int pos = atomicAdd(&cursor[d], 1);
            csr_src[pos] = src[i];
        }
        return;
    }
    // ---- gemm1 part (R9-exact) ----
    const int K = 1024, N = 256;
    int tid = threadIdx.x;
    int lane = tid & 63;
    int w = tid >> 6;
    int wm = w >> 1, wn = w & 1;          // wave covers 64 rows x 128 cols
    int m0 = blockIdx.x * 128;

    const float* srow[4];
    int soff[4];
    #pragma unroll
    for (int l = 0; l < 4; ++l) {
        int slot = l * 256 + tid;
        int m = slot >> 3, hc = slot & 7;
        int c = hc >> 1;
        int row = m0 + m; if (row >= M) row = M - 1;
        srow[l] = A + (size_t)row * K + hc * 4;
        soff[l] = (m * 4 + (c ^ ((m >> 1) & 3))) * 8 + (hc & 1) * 4;
    }
    int afrag_off[4];
    #pragma unroll
    for (int mt = 0; mt < 4; ++mt) {
        int r = wm * 64 + mt * 16 + (lane & 15);
        int cq = lane >> 4;
        afrag_off[mt] = (r * 4 + (cq ^ ((r >> 1) & 3))) * 8;
    }
    const ushort* bbase[8];
    #pragma unroll
    for (int nt = 0; nt < 8; ++nt) {
        int ntile = wn * 8 + nt;
        bbase[nt] = Bp + ((size_t)(ntile * 32) * 64 + lane) * 8;
    }

    f32x4 acc[4][8] = {};
    float4 v[4];
    #pragma unroll
    for (int l = 0; l < 4; ++l) v[l] = *(const float4*)(srow[l]);

    for (int kc = 0; kc < 32; ++kc) {
        ushort* At = Atile[kc & 1];
        #pragma unroll
        for (int l = 0; l < 4; ++l) {
            ushort4 b;
            b.x = f2bf(v[l].x); b.y = f2bf(v[l].y);
            b.z = f2bf(v[l].z); b.w = f2bf(v[l].w);
            *(ushort4*)&At[soff[l]] = b;
        }
        __syncthreads();
        // prefetch next A chunk AFTER the barrier: in flight during MFMAs
        if (kc < 31) {
            #pragma unroll
            for (int l = 0; l < 4; ++l)
                v[l] = *(const float4*)(srow[l] + (kc + 1) * 32);
        }
        bf16x8 afr[4];
        #pragma unroll
        for (int mt = 0; mt < 4; ++mt)
            afr[mt] = *(const bf16x8*)&At[afrag_off[mt]];
        #pragma unroll
        for (int nt = 0; nt < 8; ++nt) {
            bf16x8 bfr = *(const bf16x8*)(bbase[nt] + (size_t)kc * 64 * 8);
            #pragma unroll
            for (int mt = 0; mt < 4; ++mt)
                acc[mt][nt] = __builtin_amdgcn_mfma_f32_16x16x32_bf16(afr[mt], bfr, acc[mt][nt], 0, 0, 0);
        }
    }

    // epilogue: C write (bf16) + fused attention logits (2 heads per wave)
    float a_s[8], a_d[8];
    #pragma unroll
    for (int nt = 0; nt < 8; ++nt) {
        int col = wn * 128 + nt * 16 + (lane & 15);   // head = col>>6
        a_s[nt] = asrc[col];
        a_d[nt] = adst[col];
    }
    #pragma unroll
    for (int mt = 0; mt < 4; ++mt) {
        #pragma unroll
        for (int nt = 0; nt < 8; ++nt) {
            int col = wn * 128 + nt * 16 + (lane & 15);
            #pragma unroll
            for (int r = 0; r < 4; ++r) {
                int row = m0 + wm * 64 + mt * 16 + (lane >> 4) * 4 + r;
                if (row < M) C[(size_t)row * N + col] = f2bf(acc[mt][nt][r]);
            }
        }
        #pragma unroll
        for (int hg = 0; hg < 2; ++hg) {         // head group: nt 4hg..4hg+3
            int head = wn * 2 + hg;
            #pragma unroll
            for (int r = 0; r < 4; ++r) {
                int row = m0 + wm * 64 + mt * 16 + (lane >> 4) * 4 + r;
                float s = 0.f, d = 0.f;
                #pragma unroll
                for (int q = 0; q < 4; ++q) {
                    float c = acc[mt][4 * hg + q][r];
                    s = fmaf(c, a_s[4 * hg + q], s);
                    d = fmaf(c, a_d[4 * hg + q], d);
                }
                #pragma unroll
                for (int off = 1; off < 16; off <<= 1) {
                    s += __shfl_xor(s, off, 64);
                    d += __shfl_xor(d, off, 64);
                }
                if ((lane & 15) == 0 && row < M) {
                    als[row * 4 + head] = s;
                    ald[row * 4 + head] = d;
                }
            }
        }
    }
}

// ---------------------------------------------------------------------------
// bf16 MFMA GEMM, layer 2: h2b[M,64](bf16) = x2b[M,256](bf16) @ W2. (R1-exact)
__global__ __launch_bounds__(256) void gemm2_mfma(const ushort* __restrict__ Ab,
                                                  const ushort* __restrict__ Bp,
                                                  ushort* __restrict__ C,
                                                  const float* __restrict__ asrc,
                                                  const float* __restrict__ adst,
                                                  float* __restrict__ als,
                                                  float* __restrict__ ald,
                                                  int M) {
    int tid = threadIdx.x;
    int lane = tid & 63;
    int w = tid >> 6;
    int m0 = blockIdx.x * 128 + w * 32;

    f32x4 acc[2][4] = {};
    #pragma unroll 2
    for (int kc = 0; kc < 8; ++kc) {
        bf16x8 afr[2];
        #pragma unroll
        for (int mt = 0; mt < 2; ++mt) {
            int r = m0 + mt * 16 + (lane & 15);
            if (r >= M) r = M - 1;
            afr[mt] = *(const bf16x8*)&Ab[(size_t)r * 256 + kc * 32 + (lane >> 4) * 8];
        }
        #pragma unroll
        for (int nt = 0; nt < 4; ++nt) {
            bf16x8 bfr = *(const bf16x8*)&Bp[((nt * 8 + kc) * 64 + lane) * 8];
            acc[0][nt] = __builtin_amdgcn_mfma_f32_16x16x32_bf16(afr[0], bfr, acc[0][nt], 0, 0, 0);
            acc[1][nt] = __builtin_amdgcn_mfma_f32_16x16x32_bf16(afr[1], bfr, acc[1][nt], 0, 0, 0);
        }
    }
    float a_s[4], a_d[4];
    #pragma unroll
    for (int nt = 0; nt < 4; ++nt) {
        a_s[nt] = asrc[nt * 16 + (lane & 15)];
        a_d[nt] = adst[nt * 16 + (lane & 15)];
    }
    #pragma unroll
    for (int mt = 0; mt < 2; ++mt) {
        #pragma unroll
        for (int nt = 0; nt < 4; ++nt) {
            int col = nt * 16 + (lane & 15);
            #pragma unroll
            for (int r = 0; r < 4; ++r) {
                int row = m0 + mt * 16 + (lane >> 4) * 4 + r;
                if (row < M) C[(size_t)row * 64 + col] = f2bf(acc[mt][nt][r]);
            }
        }
        #pragma unroll
        for (int r = 0; r < 4; ++r) {
            int row = m0 + mt * 16 + (lane >> 4) * 4 + r;
            float s = 0.f, d = 0.f;
            #pragma unroll
            for (int nt = 0; nt < 4; ++nt) {
                float c = acc[mt][nt][r];
                s = fmaf(c, a_s[nt], s);
                d = fmaf(c, a_d[nt], d);
            }
            #pragma unroll
            for (int off = 1; off < 16; off <<= 1) {
                s += __shfl_xor(s, off, 64);
                d += __shfl_xor(d, off, 64);
            }
            if ((lane & 15) == 0 && row < M) {
                als[row] = s;
                ald[row] = d;
            }
        }
    }
}

// ---------------------------------------------------------------------------
__device__ __forceinline__ float wave_reduce_sum(float v) {
    #pragma unroll
    for (int off = 32; off > 0; off >>= 1) v += __shfl_xor(v, off, 64);
    return v;
}

__device__ __forceinline__ float edge_w(float e) {
    e = (e > 0.f) ? e : NEG_SLOPE * e;
    return __expf(e);
}

// agg1: 4 nodes/block, one full wave per node (512-B row across 64 lanes).
// Two-phase per <=64-edge chunk: staged srcs + precomputed exp-weights in
// wave-private LDS, then an unrolled gather loop with >=4 independent row
// gathers in flight. No __syncthreads anywhere. (R1 v1-exact: best measured)
__global__ __launch_bounds__(256) void agg1_kernel(const ushort* __restrict__ h,
                                                   const float* __restrict__ als,
                                                   const float* __restrict__ ald,
                                                   const int* __restrict__ indptr,
                                                   const int* __restrict__ csr_src,
                                                   const float* __restrict__ bias,
                                                   ushort* __restrict__ out, int N) {
    __shared__ int   s_s[4][64];
    __shared__ float s_w[4][64][4];
    int wv   = threadIdx.x >> 6;
    int lane = threadIdx.x & 63;
    int n = blockIdx.x * 4 + wv;
    if (n >= N) return;
    int hd = lane >> 4;
    int beg = indptr[n], end = indptr[n + 1];
    float4 aldv = *(const float4*)&ald[n * 4];

    float4 acc = make_float4(0.f, 0.f, 0.f, 0.f);
    float den = 0.f;

    for (int base = beg; base < end; base += 64) {
        int cnt = end - base; if (cnt > 64) cnt = 64;
        if (lane < cnt) {
            int s = csr_src[base + lane];
            s_s[wv][lane] = s;
            float4 av = *(const float4*)&als[s * 4];
            s_w[wv][lane][0] = edge_w(av.x + aldv.x);
            s_w[wv][lane][1] = edge_w(av.y + aldv.y);
            s_w[wv][lane][2] = edge_w(av.z + aldv.z);
            s_w[wv][lane][3] = edge_w(av.w + aldv.w);
        }
        // wave-private LDS, lock-step wave: no barrier needed
        #pragma unroll 4
        for (int e = 0; e < cnt; ++e) {
            int s = s_s[wv][e];                     // broadcast
            float wt = s_w[wv][e][hd];              // 4-addr broadcast
            ushort4 a = *(const ushort4*)&h[(size_t)s * 256 + lane * 4];
            acc.x = fmaf(wt, bf2f(a.x), acc.x);
            acc.y = fmaf(wt, bf2f(a.y), acc.y);
            acc.z = fmaf(wt, bf2f(a.z), acc.z);
            acc.w = fmaf(wt, bf2f(a.w), acc.w);
            den += wt;
        }
    }

    float inv = 1.0f / den;
    float4 bv = *(const float4*)&bias[lane * 4];
    float o0 = acc.x * inv + bv.x, o1 = acc.y * inv + bv.y;
    float o2 = acc.z * inv + bv.z, o3 = acc.w * inv + bv.w;
    o0 = (o0 > 0.f) ? o0 : (__expf(o0) - 1.0f);
    o1 = (o1 > 0.f) ? o1 : (__expf(o1) - 1.0f);
    o2 = (o2 > 0.f) ? o2 : (__expf(o2) - 1.0f);
    o3 = (o3 > 0.f) ? o3 : (__expf(o3) - 1.0f);
    ushort4 ob; ob.x = f2bf(o0); ob.y = f2bf(o1); ob.z = f2bf(o2); ob.w = f2bf(o3);
    *(ushort4*)&out[(size_t)n * 256 + lane * 4] = ob;
}

// agg2: 8 nodes/block, one half-wave per node (128-B row across 32 lanes).
// Same two-phase staged-gather structure as agg1. (R1 v1-exact)
__global__ __launch_bounds__(256) void agg2_kernel(const ushort* __restrict__ h,
                                                   const float* __restrict__ als,
                                                   const float* __restrict__ ald,
                                                   const int* __restrict__ indptr,
                                                   const int* __restrict__ csr_src,
                                                   const float* __restrict__ bias,
                                                   float* __restrict__ out, int N) {
    __shared__ int   s_s[8][32];
    __shared__ float s_w[8][32];
    int tid = threadIdx.x;
    int sl  = tid >> 5;        // half-wave slice 0..7
    int l32 = tid & 31;
    int n = blockIdx.x * 8 + sl;
    if (n >= N) return;
    int beg = indptr[n], end = indptr[n + 1];
    float ald_n = ald[n];

    float2 acc = make_float2(0.f, 0.f);
    float den = 0.f;

    for (int base = beg; base < end; base += 32) {
        int cnt = end - base; if (cnt > 32) cnt = 32;
        if (l32 < cnt) {
            int s = csr_src[base + l32];
            s_s[sl][l32] = s;
            s_w[sl][l32] = edge_w(als[s] + ald_n);
        }
        #pragma unroll 4
        for (int e = 0; e < cnt; ++e) {
            int s = s_s[sl][e];
            float wt = s_w[sl][e];
            ushort2 hv = *(const ushort2*)&h[(size_t)s * 64 + l32 * 2];
            acc.x = fmaf(wt, bf2f(hv.x), acc.x);
            acc.y = fmaf(wt, bf2f(hv.y), acc.y);
            den += wt;
        }
    }

    float inv = 1.0f / den;
    float o0 = acc.x * inv + bias[l32 * 2];
    float o1 = acc.y * inv + bias[l32 * 2 + 1];
    o0 = (o0 > 0.f) ? o0 : (__expf(o0) - 1.0f);
    o1 = (o1 > 0.f) ? o1 : (__expf(o1) - 1.0f);
    *(float2*)&out[(size_t)n * 64 + l32 * 2] = make_float2(o0, o1);
}

// Fused mean-pool + FC: one block per graph (batch sorted => contiguous range).
__global__ __launch_bounds__(256) void pool_fc_kernel(const float* __restrict__ hfin,
                                                      const int* __restrict__ batch,
                                                      const float* __restrict__ fc_w,
                                                      const float* __restrict__ fc_b,
                                                      float* __restrict__ out, int N) {
    __shared__ float lacc[4][64];
    int g = blockIdx.x;
    int beg, end;
    {
        int lo = 0, hi = N;
        while (lo < hi) { int mid = (lo + hi) >> 1; if (batch[mid] < g) lo = mid + 1; else hi = mid; }
        beg = lo;
        lo = beg; hi = N;
        while (lo < hi) { int mid = (lo + hi) >> 1; if (batch[mid] < g + 1) lo = mid + 1; else hi = mid; }
        end = lo;
    }
    int lane = threadIdx.x & 63;
    int wv = threadIdx.x >> 6;
    float acc = 0.f;
    for (int n = beg + wv; n < end; n += 4)
        acc += hfin[(size_t)n * 64 + lane];
    lacc[wv][lane] = acc;
    __syncthreads();
    if (wv == 0) {
        float s = lacc[0][lane] + lacc[1][lane] + lacc[2][lane] + lacc[3][lane];
        float cnt = fmaxf((float)(end - beg), 1.0f);
        float pooled = s / cnt;
        float p0 = wave_reduce_sum(pooled * fc_w[lane * 2 + 0]);
        float p1 = wave_reduce_sum(pooled * fc_w[lane * 2 + 1]);
        if (lane == 0) {
            out[g * 2 + 0] = p0 + fc_b[0];
            out[g * 2 + 1] = p1 + fc_b[1];
        }
    }
}

// ---------------------------------------------------------------------------
extern "C" void kernel_launch(void* const* d_in, const int* in_sizes, int n_in,
                              void* d_out, int out_size, void* d_ws, size_t ws_size,
                              hipStream_t stream) {
    const float* x      = (const float*)d_in[0];
    const int*   ei     = (const int*)d_in[1];
    const int*   batch  = (const int*)d_in[2];
    const float* W1     = (const float*)d_in[3];
    const float* asrc1  = (const float*)d_in[4];
    const float* adst1  = (const float*)d_in[5];
    const float* b1     = (const float*)d_in[6];
    const float* W2     = (const float*)d_in[7];
    const float* asrc2  = (const float*)d_in[8];
    const float* adst2  = (const float*)d_in[9];
    const float* b2     = (const float*)d_in[10];
    const float* fc_w   = (const float*)d_in[11];
    const float* fc_b   = (const float*)d_in[12];
    float* out          = (float*)d_out;

    const int N = in_sizes[2];          // 50000
    const int E = in_sizes[1] / 2;      // 850000
    const int* src = ei;
    const int* dst = ei + E;

    float* ws = (float*)d_ws;
    int*    counts  = (int*)(ws + WS_COUNTS);
    int*    indptr  = (int*)(ws + WS_INDPTR);
    int*    cursor  = (int*)(ws + WS_CURSOR);
    int*    csr_src = (int*)(ws + WS_CSRSRC);
    int*    bsum    = (int*)(ws + WS_BSUM);
    float*  al_s1   = ws + WS_ALS1;
    float*  al_d1   = ws + WS_ALD1;
    float*  al_s2   = ws + WS_ALS2;
    float*  al_d2   = ws + WS_ALD2;
    ushort* bp      = (ushort*)(ws + WS_BP);
    ushort* bp2     = (ushort*)(ws + WS_BP2);
    ushort* h1b     = (ushort*)(ws + WS_H1B);
    ushort* x2b     = (ushort*)(ws + WS_X2B);
    ushort* h2b     = (ushort*)(ws + WS_H2B);
    float*  hfin    = ws + WS_HFIN;

    const int nb  = (N + 1023) / 1024;       // scan blocks (<=64)
    const int nbe = (E + 255) / 256;         // edge blocks (3321)
    const int ng1 = (N + 127) / 128;         // gemm1 blocks (391)

    // 1. zero counts (memset node) + fused pack W1/W2 + hist
    hipMemsetAsync(counts, 0, (size_t)N * sizeof(int), stream);
    packhist_kernel<<<1088 + nbe, 256, 0, stream>>>(W1, W2, bp, bp2, dst, counts, E);
    // 2. scan chain (small, serial)
    scan1_kernel<<<nb, 1024, 0, stream>>>(counts, indptr, bsum, N);
    scan2_kernel<<<1, 64, 0, stream>>>(bsum, nb);
    scan3_kernel<<<nb, 1024, 0, stream>>>(counts, indptr, cursor, bsum, N);
    // 3. co-launched gemm1 + CSR fill -> h1b + logits + csr_src
    gemm1_fill<<<ng1 + nbe, 256, 0, stream>>>(
        x, bp, h1b, asrc1, adst1, al_s1, al_d1, N, ng1,
        src, dst, cursor, csr_src, E);
    // 4. aggregate (inline softmax weights) + bias + ELU -> x2b (bf16)
    agg1_kernel<<<(N + 3) / 4, 256, 0, stream>>>(h1b, al_s1, al_d1, indptr, csr_src, b1, x2b, N);
    // 5. layer 2 GEMM -> h2b (bf16) + fused att logits
    gemm2_mfma<<<(N + 127) / 128, 256, 0, stream>>>(
        x2b, bp2, h2b, asrc2, adst2, al_s2, al_d2, N);
    // 6. aggregate (inline softmax weights) + bias + ELU -> hfin (fp32)
    agg2_kernel<<<(N + 7) / 8, 256, 0, stream>>>(h2b, al_s2, al_d2, indptr, csr_src, b2, hfin, N);
    // 7. fused mean pool + FC
    pool_fc_kernel<<<NGRAPHS, 256, 0, stream>>>(hfin, batch, fc_w, fc_b, out, N);
}